// Round 7
// baseline (106.912 us; speedup 1.0000x reference)
//
#include <hip/hip_runtime.h>
#include <math.h>

// Problem constants (from reference)
constexpr int ROWS = 32768;   // 2*16*1024
constexpr int COLS = 2048;
constexpr int K    = 512;
constexpr float EPS = 1e-5f;
constexpr int WPB  = 4;       // waves per block (1 row per wave) — r4 structure

typedef float f32x4 __attribute__((ext_vector_type(4)));
typedef int   i32x4 __attribute__((ext_vector_type(4)));

// Wave-level fences (wave64 lockstep; each wave owns a private LDS slice, so
// no workgroup barriers are needed anywhere). sched_barrier(0) after each
// inline-asm waitcnt stops hipcc hoisting dependent ops past it (rule #18).
__device__ __forceinline__ void wave_vm_fence() {
    asm volatile("s_waitcnt vmcnt(0)" ::: "memory");
    __builtin_amdgcn_sched_barrier(0);
}
__device__ __forceinline__ void wave_lds_fence() {
    asm volatile("s_waitcnt lgkmcnt(0)" ::: "memory");
    __builtin_amdgcn_sched_barrier(0);
}

// Each wave (64 lanes) owns one row, fully independent of other waves:
//  1. DMA the 2048-float row into LDS via global_load_lds (16B/lane)
//  2. gather 8 values/lane via col_indices (idx loads CACHED -> L3-resident
//     across replays; only change vs r4 where they were NT)
//  3. wave shfl reductions: mean/var -> normalize -> max -> exp/sum -> softmax
//  4. zero the LDS row, scatter softmax values, write out coalesced NT float4
__global__ __launch_bounds__(256) void fused_gather_ln_softmax_scatter(
    const float* __restrict__ x,
    const float* __restrict__ gamma,
    const float* __restrict__ beta,
    const int*   __restrict__ cidx,
    float*       __restrict__ out)
{
    __shared__ float lds[WPB][COLS];   // 32 KiB
    const int lane = threadIdx.x & 63;
    const int wv   = threadIdx.x >> 6;
    const int row  = blockIdx.x * WPB + wv;   // grid sized exactly ROWS/WPB

    // ---- stage row into LDS: 8 x global_load_lds_dwordx4 per wave ----
    const f32x4* x4 = reinterpret_cast<const f32x4*>(x + (size_t)row * COLS);
    #pragma unroll
    for (int i = 0; i < 8; ++i) {
        // global src is per-lane; LDS dest base is wave-uniform, HW adds lane*16
        __builtin_amdgcn_global_load_lds(
            reinterpret_cast<const unsigned int*>(&x4[i * 64 + lane]),
            reinterpret_cast<unsigned int*>(&lds[wv][i * 256]),
            16, 0, 0);
    }

    // ---- load this lane's 8 column indices (coalesced int4 x2, CACHED) ----
    const i32x4* i4 = reinterpret_cast<const i32x4*>(cidx + (size_t)row * K) + lane * 2;
    const i32x4 ia = i4[0];
    const i32x4 ib = i4[1];
    const int idx[8] = {ia.x, ia.y, ia.z, ia.w, ib.x, ib.y, ib.z, ib.w};

    // ---- gamma/beta for this lane's K-positions (k = lane*8 + j) ----
    const f32x4* g4 = reinterpret_cast<const f32x4*>(gamma) + lane * 2;
    const f32x4* b4 = reinterpret_cast<const f32x4*>(beta)  + lane * 2;
    const f32x4 ga = g4[0], gb = g4[1];
    const f32x4 ba = b4[0], bb = b4[1];
    const float g[8] = {ga.x, ga.y, ga.z, ga.w, gb.x, gb.y, gb.z, gb.w};
    const float b[8] = {ba.x, ba.y, ba.z, ba.w, bb.x, bb.y, bb.z, bb.w};

    wave_vm_fence();    // DMA staging (vmcnt) complete -> LDS row valid

    // ---- gather from LDS ----
    float v[8];
    #pragma unroll
    for (int j = 0; j < 8; ++j) v[j] = lds[wv][idx[j]];

    // ---- mean / biased variance over K=512 (wave reduction) ----
    float s = 0.f, ss = 0.f;
    #pragma unroll
    for (int j = 0; j < 8; ++j) { s += v[j]; ss += v[j] * v[j]; }
    #pragma unroll
    for (int off = 32; off >= 1; off >>= 1) {
        s  += __shfl_xor(s,  off, 64);
        ss += __shfl_xor(ss, off, 64);
    }
    const float mu   = s * (1.f / K);
    const float var  = ss * (1.f / K) - mu * mu;
    const float rstd = rsqrtf(var + EPS);

    // ---- normalize + row max ----
    float xn[8];
    float m = -INFINITY;
    #pragma unroll
    for (int j = 0; j < 8; ++j) {
        xn[j] = (v[j] - mu) * rstd * g[j] + b[j];
        m = fmaxf(m, xn[j]);
    }
    #pragma unroll
    for (int off = 32; off >= 1; off >>= 1)
        m = fmaxf(m, __shfl_xor(m, off, 64));

    // ---- exp + sum ----
    float p[8], ps = 0.f;
    #pragma unroll
    for (int j = 0; j < 8; ++j) { p[j] = __expf(xn[j] - m); ps += p[j]; }
    #pragma unroll
    for (int off = 32; off >= 1; off >>= 1)
        ps += __shfl_xor(ps, off, 64);
    const float inv = 1.f / ps;

    // Per-wave DS ops execute in order: gather reads were issued before the
    // zero/scatter writes below (compiler preserves may-alias ds order).

    // ---- zero LDS row, scatter softmax values ----
    f32x4* l4 = reinterpret_cast<f32x4*>(lds[wv]);
    const f32x4 z4 = (f32x4)(0.f);
    #pragma unroll
    for (int i = 0; i < 8; ++i)
        l4[i * 64 + lane] = z4;
    #pragma unroll
    for (int j = 0; j < 8; ++j)
        lds[wv][idx[j]] = p[j] * inv;

    wave_lds_fence();   // zero+scatter visible wave-wide before readback

    // ---- coalesced nontemporal store of the full row ----
    f32x4* o4 = reinterpret_cast<f32x4*>(out + (size_t)row * COLS);
    #pragma unroll
    for (int i = 0; i < 8; ++i)
        __builtin_nontemporal_store(l4[i * 64 + lane], &o4[i * 64 + lane]);
}

extern "C" void kernel_launch(void* const* d_in, const int* in_sizes, int n_in,
                              void* d_out, int out_size, void* d_ws, size_t ws_size,
                              hipStream_t stream) {
    const float* x     = (const float*)d_in[0];
    const float* gamma = (const float*)d_in[1];
    const float* beta  = (const float*)d_in[2];
    const int*   cidx  = (const int*)d_in[3];
    float* out = (float*)d_out;

    dim3 grid(ROWS / WPB);   // 8192 blocks
    dim3 block(256);
    hipLaunchKernelGGL(fused_gather_ln_softmax_scatter, grid, block, 0, stream,
                       x, gamma, beta, cidx, out);
}

// Round 8
// 99.141 us; speedup vs baseline: 1.0784x; 1.0784x over previous
//
#include <hip/hip_runtime.h>
#include <math.h>

// Problem constants (from reference)
constexpr int ROWS = 32768;   // 2*16*1024
constexpr int COLS = 2048;
constexpr int K    = 512;
constexpr float EPS = 1e-5f;
constexpr int WPB  = 4;       // waves per block (1 row in flight per wave)
constexpr int RPW  = 8;       // rows per wave (persistent loop)
// grid = ROWS/(WPB*RPW) = 1024 blocks = exactly 4 per CU, uniform, no tail

typedef float f32x4 __attribute__((ext_vector_type(4)));
typedef int   i32x4 __attribute__((ext_vector_type(4)));

// Pin instruction order (also used standalone between vmem issue groups so the
// scheduler can't interleave stores ahead of the DMA group — the vmcnt ledger
// depends on issue order).
__device__ __forceinline__ void sbar() { __builtin_amdgcn_sched_barrier(0); }

// Wave-level fences (wave64 lockstep; each wave owns a private LDS slice, so
// no workgroup barriers are needed anywhere). sched_barrier(0) after each
// inline-asm waitcnt stops hipcc hoisting dependent ops past it (rule #18).
__device__ __forceinline__ void wave_lds_fence() {
    asm volatile("s_waitcnt lgkmcnt(0)" ::: "memory");
    __builtin_amdgcn_sched_barrier(0);
}
#define VMWAIT(N) do { asm volatile("s_waitcnt vmcnt(" #N ")" ::: "memory"); \
                       __builtin_amdgcn_sched_barrier(0); } while (0)

// Persistent wave, 8 rows each, single 8KB buffer (r4 structure per row):
//  prologue: DMA(row0)+idx(row0), vmcnt(0)
//  iter r:   gather -> LN -> softmax -> zero+scatter -> readback to regs
//            -> issue DMA(r+1)+idx(r+1) -> NT-store row r -> vmcnt(8)
__global__ __launch_bounds__(256) void fused_gather_ln_softmax_scatter(
    const float* __restrict__ x,
    const float* __restrict__ gamma,
    const float* __restrict__ beta,
    const int*   __restrict__ cidx,
    float*       __restrict__ out)
{
    __shared__ float lds[WPB][COLS];   // 32 KiB
    const int lane = threadIdx.x & 63;
    const int wv   = threadIdx.x >> 6;
    const int gw   = blockIdx.x * WPB + wv;
    const int row0 = gw * RPW;

    float* buf = lds[wv];
    f32x4* l4  = reinterpret_cast<f32x4*>(buf);

    // ---- issue one row's staging DMA: 8 x global_load_lds_dwordx4 ----
    auto dma_row = [&](int r) {
        const f32x4* src = reinterpret_cast<const f32x4*>(x + (size_t)(row0 + r) * COLS);
        #pragma unroll
        for (int ii = 0; ii < 8; ++ii)
            __builtin_amdgcn_global_load_lds(
                reinterpret_cast<const unsigned int*>(src + ii * 64 + lane),
                reinterpret_cast<unsigned int*>(buf + ii * 256),
                16, 0, 0);
    };
    // ---- issue one row's index loads (2 vmem ops, NT — r4/r7 A/B says NT) ----
    auto idx_load = [&](int r, i32x4& a, i32x4& b) {
        const i32x4* ip = reinterpret_cast<const i32x4*>(cidx + (size_t)(row0 + r) * K) + lane * 2;
        a = __builtin_nontemporal_load(ip);
        b = __builtin_nontemporal_load(ip + 1);
    };

    // ---- gamma/beta once per wave (k = lane*8 + j) ----
    const f32x4* g4 = reinterpret_cast<const f32x4*>(gamma) + lane * 2;
    const f32x4* b4 = reinterpret_cast<const f32x4*>(beta)  + lane * 2;
    const f32x4 ga = g4[0], gb = g4[1];
    const f32x4 ba = b4[0], bb = b4[1];
    const float g[8] = {ga.x, ga.y, ga.z, ga.w, gb.x, gb.y, gb.z, gb.w};
    const float b[8] = {ba.x, ba.y, ba.z, ba.w, bb.x, bb.y, bb.z, bb.w};

    // ---- prologue ----
    i32x4 ia, ib, na, nb;
    dma_row(0);
    idx_load(0, ia, ib);
    sbar();
    VMWAIT(0);                 // first row staged (nothing else in flight)

    #pragma unroll
    for (int r = 0; r < RPW; ++r) {
        const int idx[8] = {ia.x, ia.y, ia.z, ia.w, ib.x, ib.y, ib.z, ib.w};

        // ---- gather from LDS ----
        float v[8];
        #pragma unroll
        for (int j = 0; j < 8; ++j) v[j] = buf[idx[j]];

        // ---- mean / biased variance over K=512 (wave reduction) ----
        float s = 0.f, ss = 0.f;
        #pragma unroll
        for (int j = 0; j < 8; ++j) { s += v[j]; ss += v[j] * v[j]; }
        #pragma unroll
        for (int off = 32; off >= 1; off >>= 1) {
            s  += __shfl_xor(s,  off, 64);
            ss += __shfl_xor(ss, off, 64);
        }
        const float mu   = s * (1.f / K);
        const float var  = ss * (1.f / K) - mu * mu;
        const float rstd = rsqrtf(var + EPS);

        // ---- normalize + row max ----
        float xn[8];
        float m = -INFINITY;
        #pragma unroll
        for (int j = 0; j < 8; ++j) {
            xn[j] = (v[j] - mu) * rstd * g[j] + b[j];
            m = fmaxf(m, xn[j]);
        }
        #pragma unroll
        for (int off = 32; off >= 1; off >>= 1)
            m = fmaxf(m, __shfl_xor(m, off, 64));

        // ---- exp + sum ----
        float p[8], ps = 0.f;
        #pragma unroll
        for (int j = 0; j < 8; ++j) { p[j] = __expf(xn[j] - m); ps += p[j]; }
        #pragma unroll
        for (int off = 32; off >= 1; off >>= 1)
            ps += __shfl_xor(ps, off, 64);
        const float inv = 1.f / ps;

        // ---- zero row + scatter (per-wave DS ops retire in order;
        //      gather reads above precede these writes) ----
        const f32x4 z4 = (f32x4)(0.f);
        #pragma unroll
        for (int i = 0; i < 8; ++i) l4[i * 64 + lane] = z4;
        #pragma unroll
        for (int j = 0; j < 8; ++j) buf[idx[j]] = p[j] * inv;

        wave_lds_fence();       // scatter visible wave-wide

        // ---- read the assembled row back into registers ----
        f32x4 o[8];
        #pragma unroll
        for (int i = 0; i < 8; ++i) o[i] = l4[i * 64 + lane];

        wave_lds_fence();       // readback complete -> buffer free for next DMA

        // ---- issue next row's DMA + idx BEFORE the stores (ledger order) ----
        if (r + 1 < RPW) {
            dma_row(r + 1);
            idx_load(r + 1, na, nb);
        }
        sbar();                 // pin: [dma,idx] strictly before stores

        // ---- coalesced nontemporal store of row r ----
        f32x4* o4 = reinterpret_cast<f32x4*>(out + (size_t)(row0 + r) * COLS);
        #pragma unroll
        for (int i = 0; i < 8; ++i)
            __builtin_nontemporal_store(o[i], &o4[i * 64 + lane]);

        if (r + 1 < RPW) {
            VMWAIT(8);          // retire dma+idx (10 before the 8 stores); stores may fly
            ia = na; ib = nb;
        }
    }
}

extern "C" void kernel_launch(void* const* d_in, const int* in_sizes, int n_in,
                              void* d_out, int out_size, void* d_ws, size_t ws_size,
                              hipStream_t stream) {
    const float* x     = (const float*)d_in[0];
    const float* gamma = (const float*)d_in[1];
    const float* beta  = (const float*)d_in[2];
    const int*   cidx  = (const int*)d_in[3];
    float* out = (float*)d_out;

    dim3 grid(ROWS / (WPB * RPW));   // 1024 blocks = 4 per CU, uniform
    dim3 block(256);
    hipLaunchKernelGGL(fused_gather_ln_softmax_scatter, grid, block, 0, stream,
                       x, gamma, beta, cidx, out);
}

// Round 9
// 92.882 us; speedup vs baseline: 1.1511x; 1.0674x over previous
//
#include <hip/hip_runtime.h>
#include <math.h>

// Problem constants (from reference)
constexpr int ROWS = 32768;   // 2*16*1024
constexpr int COLS = 2048;
constexpr int K    = 512;
constexpr float EPS = 1e-5f;
constexpr int WPB  = 4;       // waves per block (1 row per wave)

// clang ext_vector types — required by __builtin_nontemporal_load/store
typedef float f32x4 __attribute__((ext_vector_type(4)));
typedef int   i32x4 __attribute__((ext_vector_type(4)));

// Wave-level fences (wave64 lockstep; each wave owns a private LDS slice, so
// no workgroup barriers are needed anywhere). sched_barrier(0) after each
// inline-asm waitcnt stops hipcc hoisting dependent ops past it (rule #18).
__device__ __forceinline__ void wave_vm_fence() {
    asm volatile("s_waitcnt vmcnt(0)" ::: "memory");
    __builtin_amdgcn_sched_barrier(0);
}
__device__ __forceinline__ void wave_lds_fence() {
    asm volatile("s_waitcnt lgkmcnt(0)" ::: "memory");
    __builtin_amdgcn_sched_barrier(0);
}

// r4 structure (best measured: 92.9 us — at the mixed-stream ceiling).
// Each wave (64 lanes) owns one row, fully independent of other waves:
//  1. DMA the 2048-float row into LDS via global_load_lds (16B/lane, no VGPR
//     round-trip; dest = wave-uniform base + lane*16 — exactly our layout)
//  2. gather 8 values/lane via col_indices (NT idx loads — r7 A/B: cached
//     idx loads cost +15% at equal HBM bytes)
//  3. wave shfl reductions: mean/var -> normalize -> max -> exp/sum -> softmax
//  4. zero the LDS row, scatter softmax values, write out coalesced NT float4
__global__ __launch_bounds__(256) void fused_gather_ln_softmax_scatter(
    const float* __restrict__ x,
    const float* __restrict__ gamma,
    const float* __restrict__ beta,
    const int*   __restrict__ cidx,
    float*       __restrict__ out)
{
    __shared__ float lds[WPB][COLS];   // 32 KiB
    const int lane = threadIdx.x & 63;
    const int wv   = threadIdx.x >> 6;
    const int row  = blockIdx.x * WPB + wv;   // grid sized exactly ROWS/WPB

    // ---- stage row into LDS: 8 x global_load_lds_dwordx4 per wave ----
    const f32x4* x4 = reinterpret_cast<const f32x4*>(x + (size_t)row * COLS);
    #pragma unroll
    for (int i = 0; i < 8; ++i) {
        // global src is per-lane; LDS dest base is wave-uniform, HW adds lane*16
        __builtin_amdgcn_global_load_lds(
            reinterpret_cast<const unsigned int*>(&x4[i * 64 + lane]),
            reinterpret_cast<unsigned int*>(&lds[wv][i * 256]),
            16, 0, 0);
    }

    // ---- load this lane's 8 column indices (coalesced int4 x2, NT) ----
    const i32x4* i4 = reinterpret_cast<const i32x4*>(cidx + (size_t)row * K) + lane * 2;
    const i32x4 ia = __builtin_nontemporal_load(&i4[0]);
    const i32x4 ib = __builtin_nontemporal_load(&i4[1]);
    const int idx[8] = {ia.x, ia.y, ia.z, ia.w, ib.x, ib.y, ib.z, ib.w};

    // ---- gamma/beta for this lane's K-positions (k = lane*8 + j) ----
    const f32x4* g4 = reinterpret_cast<const f32x4*>(gamma) + lane * 2;
    const f32x4* b4 = reinterpret_cast<const f32x4*>(beta)  + lane * 2;
    const f32x4 ga = g4[0], gb = g4[1];
    const f32x4 ba = b4[0], bb = b4[1];
    const float g[8] = {ga.x, ga.y, ga.z, ga.w, gb.x, gb.y, gb.z, gb.w};
    const float b[8] = {ba.x, ba.y, ba.z, ba.w, bb.x, bb.y, bb.z, bb.w};

    wave_vm_fence();    // DMA staging (vmcnt) complete -> LDS row valid

    // ---- gather from LDS ----
    float v[8];
    #pragma unroll
    for (int j = 0; j < 8; ++j) v[j] = lds[wv][idx[j]];

    // ---- mean / biased variance over K=512 (wave reduction) ----
    float s = 0.f, ss = 0.f;
    #pragma unroll
    for (int j = 0; j < 8; ++j) { s += v[j]; ss += v[j] * v[j]; }
    #pragma unroll
    for (int off = 32; off >= 1; off >>= 1) {
        s  += __shfl_xor(s,  off, 64);
        ss += __shfl_xor(ss, off, 64);
    }
    const float mu   = s * (1.f / K);
    const float var  = ss * (1.f / K) - mu * mu;
    const float rstd = rsqrtf(var + EPS);

    // ---- normalize + row max ----
    float xn[8];
    float m = -INFINITY;
    #pragma unroll
    for (int j = 0; j < 8; ++j) {
        xn[j] = (v[j] - mu) * rstd * g[j] + b[j];
        m = fmaxf(m, xn[j]);
    }
    #pragma unroll
    for (int off = 32; off >= 1; off >>= 1)
        m = fmaxf(m, __shfl_xor(m, off, 64));

    // ---- exp + sum ----
    float p[8], ps = 0.f;
    #pragma unroll
    for (int j = 0; j < 8; ++j) { p[j] = __expf(xn[j] - m); ps += p[j]; }
    #pragma unroll
    for (int off = 32; off >= 1; off >>= 1)
        ps += __shfl_xor(ps, off, 64);
    const float inv = 1.f / ps;

    // Per-wave DS ops execute in order: gather reads were issued before the
    // zero/scatter writes below (compiler preserves may-alias ds order).

    // ---- zero LDS row, scatter softmax values ----
    f32x4* l4 = reinterpret_cast<f32x4*>(lds[wv]);
    const f32x4 z4 = (f32x4)(0.f);
    #pragma unroll
    for (int i = 0; i < 8; ++i)
        l4[i * 64 + lane] = z4;
    #pragma unroll
    for (int j = 0; j < 8; ++j)
        lds[wv][idx[j]] = p[j] * inv;

    wave_lds_fence();   // zero+scatter visible wave-wide before readback

    // ---- coalesced nontemporal store of the full row ----
    f32x4* o4 = reinterpret_cast<f32x4*>(out + (size_t)row * COLS);
    #pragma unroll
    for (int i = 0; i < 8; ++i)
        __builtin_nontemporal_store(l4[i * 64 + lane], &o4[i * 64 + lane]);
}

extern "C" void kernel_launch(void* const* d_in, const int* in_sizes, int n_in,
                              void* d_out, int out_size, void* d_ws, size_t ws_size,
                              hipStream_t stream) {
    const float* x     = (const float*)d_in[0];
    const float* gamma = (const float*)d_in[1];
    const float* beta  = (const float*)d_in[2];
    const int*   cidx  = (const int*)d_in[3];
    float* out = (float*)d_out;

    dim3 grid(ROWS / WPB);   // 8192 blocks
    dim3 block(256);
    hipLaunchKernelGGL(fused_gather_ln_softmax_scatter, grid, block, 0, stream,
                       x, gamma, beta, cidx, out);
}